// Round 1
// 987.460 us; speedup vs baseline: 1.2030x; 1.2030x over previous
//
#include <hip/hip_runtime.h>
#include <cfloat>
#include <climits>
#include <math.h>

#define SRATE 22050.0
#define WMAX 512
#define RCAP 128
#define LCR 256
#define RCR 512
#define SCAP 16384
#define SLDS 12288
#define OPR 256
#define MSL 3072
#define NTW 256

// scal layout: 0 gp_bits, 1 minpos_bits, 2 median_bits, 3 has_pos, 4 n_peaks,
// 6 tail, 8 ns0, 9 ne0, 10 ns1, 11 ne1, 12 nreg0, 13 nreg1, 14 nreg1_eff, 15 n_pos
__global__ __launch_bounds__(256) void kinit_stats(const float* __restrict__ pitch, int S, unsigned* scal) {
  __shared__ int sc[256];
  __shared__ int sa[256];
  int tid = threadIdx.x;
  if (tid < 64) scal[tid] = (tid == 1) ? 0x7f800000u : 0u;
  int c = 0, a = 0;
  for (int j = tid; j < S; j += 256) {
    float v = pitch[j];
    if (v > 0.0f) c++;
    if (v > 1e-05f) a = 1;
  }
  sc[tid] = c; sa[tid] = a; __syncthreads();
  for (int st = 128; st; st >>= 1) {
    if (tid < st) { sc[tid] += sc[tid + st]; sa[tid] |= sa[tid + st]; }
    __syncthreads();
  }
  if (tid == 0) { scal[15] = (unsigned)sc[0]; scal[3] = (unsigned)sa[0]; }
}

// parallel k-th order statistic of positives: value-based rank select (tie-safe)
__global__ __launch_bounds__(512) void kmedsel(const float* __restrict__ pitch, int S, unsigned* scal) {
  __shared__ float sp[MSL];
  int tid = threadIdx.x;
  int n = (int)scal[15];
  if (n == 0) return;
  int k = (n - 1) >> 1;
  bool lds = (S <= MSL);
  if (lds) { for (int q = tid; q < S; q += 512) sp[q] = pitch[q]; __syncthreads(); }
  int j = blockIdx.x * 512 + tid;
  if (j >= S) return;
  float v = lds ? sp[j] : pitch[j];
  if (!(v > 0.0f)) return;
  int lt = 0, eq = 0;
  for (int q = 0; q < S; ++q) {
    float u = lds ? sp[q] : pitch[q];
    if (u > 0.0f && u < v) lt++;
    if (u == v) eq++;
  }
  if (lt <= k && k < lt + eq) scal[2] = __float_as_uint(v);  // all writers identical
}

__device__ __forceinline__ float interp1(const float* __restrict__ pitch, int S, double r, int t) {
  double x = ((double)t + 0.5) * r - 0.5;
  if (x < 0.0) x = 0.0;
  double sm1 = (double)(S - 1);
  if (x > sm1) x = sm1;
  double fl = floor(x);
  int i0 = (int)fl;
  int i1 = i0 + 1; if (i1 > S - 1) i1 = S - 1;
  float f = (float)(x - fl);
  return __fadd_rn(__fmul_rn(pitch[i0], __fsub_rn(1.0f, f)), __fmul_rn(pitch[i1], f));
}

// ---- fused: f0, f0s, gp=max|snd|, minpos(f0s), region transitions for both ----
__global__ __launch_bounds__(256) void kprep(const float* __restrict__ pitch, int S, int T,
                                             const float* __restrict__ snd, unsigned* scal,
                                             const int* __restrict__ steps_p, const float* __restrict__ pr_p,
                                             float* __restrict__ f0, float* __restrict__ f0s,
                                             int* s0l, int* e0l, int* s1l, int* e1l) {
  __shared__ float smax[256];
  __shared__ unsigned smin[256];
  float med = __uint_as_float(scal[2]);
  double factor = exp2((double)steps_p[0] / 12.0);
  float fac32 = (float)factor;
  float m32 = (float)((double)med * factor);
  float pr32 = pr_p[0];
  double r = (double)S / (double)T;
  float amax = 0.0f;
  unsigned lmin = 0x7f800000u;
  int stride = gridDim.x * blockDim.x;
  for (int t = blockIdx.x * blockDim.x + threadIdx.x; t < T; t += stride) {
    float v = interp1(pitch, S, r, t);
    f0[t] = v;
    float v1 = __fmul_rn(v, fac32);
    float vs = 0.0f;
    if (v1 > 0.0f) vs = __fadd_rn(m32, __fmul_rn(__fsub_rn(v1, m32), pr32));
    f0s[t] = vs;
    if (vs > 0.0f) { unsigned b = __float_as_uint(vs); if (b < lmin) lmin = b; }
    float a = fabsf(snd[t]); if (a > amax) amax = a;
    bool pv = false, pv1 = false;
    if (t > 0) {
      float pvv = interp1(pitch, S, r, t - 1);
      pv = pvv > 0.0f;
      float pm1 = __fmul_rn(pvv, fac32);
      float pvs = 0.0f;
      if (pm1 > 0.0f) pvs = __fadd_rn(m32, __fmul_rn(__fsub_rn(pm1, m32), pr32));
      pv1 = pvs > 0.0f;
    }
    bool cv = v > 0.0f, cv1 = vs > 0.0f;
    if (cv && (t == 0 || !pv))  { unsigned k = atomicAdd(scal + 8, 1u);  if (k < RCAP) s0l[k] = t; }
    if (!cv && t > 0 && pv)     { unsigned k = atomicAdd(scal + 9, 1u);  if (k < RCAP) e0l[k] = t; }
    if (cv1 && (t == 0 || !pv1)){ unsigned k = atomicAdd(scal + 10, 1u); if (k < RCAP) s1l[k] = t; }
    if (!cv1 && t > 0 && pv1)   { unsigned k = atomicAdd(scal + 11, 1u); if (k < RCAP) e1l[k] = t; }
  }
  smax[threadIdx.x] = amax; smin[threadIdx.x] = lmin; __syncthreads();
  for (int st = 128; st; st >>= 1) {
    if (threadIdx.x < st) {
      float o = smax[threadIdx.x + st]; if (o > smax[threadIdx.x]) smax[threadIdx.x] = o;
      unsigned u = smin[threadIdx.x + st]; if (u < smin[threadIdx.x]) smin[threadIdx.x] = u;
    }
    __syncthreads();
  }
  if (threadIdx.x == 0) {
    atomicMax(scal + 0, __float_as_uint(smax[0]));
    atomicMin(scal + 1, smin[0]);
  }
}

// parallel rank sort (distinct values) in LDS
__device__ void ranksort(int* a, int n, int tid, int* tmp) {
  int v = 0, rk = 0;
  if (tid < n) {
    v = a[tid];
    for (int q = 0; q < n; q++) if (a[q] < v) rk++;
  }
  __syncthreads();
  if (tid < n) tmp[rk] = v;
  __syncthreads();
  if (tid < n) a[tid] = tmp[tid];
  __syncthreads();
}

// pairing over LDS arrays; reproduces repeated _find_voiced semantics
__device__ int pair_regions_lds(float f1, int T, int* sl, int ns, int* el, int ne, int* L, int* R) {
  int b = 0;
  if (ns > 0 && sl[0] == 0) {
    if (T > 1 && f1 > 0.0f) sl[0] = 1;
    else b = 1;
  }
  int m = 0, j = 0;
  for (int k = b; k < ns; k++) {
    int Lv = sl[k];
    while (j < ne && el[j] <= Lv) j++;
    int Rv = (j < ne) ? el[j] : T;
    if (m < RCAP) { L[m] = Lv; R[m] = Rv; m++; }
  }
  return m;
}

__global__ __launch_bounds__(128) void kregsort2(const float* __restrict__ f0, const float* __restrict__ f0s,
                                                 int T, unsigned* scal,
                                                 const int* __restrict__ s0l, const int* __restrict__ e0l,
                                                 const int* __restrict__ s1l, const int* __restrict__ e1l,
                                                 int* r0L, int* r0R, int* r1L, int* r1R) {
  __shared__ int A[RCAP], B[RCAP], C[RCAP], D[RCAP];
  __shared__ int tmp[RCAP];
  __shared__ int LA[RCAP], RA[RCAP];
  int tid = threadIdx.x;
  int ns0 = min((int)scal[8], RCAP), ne0 = min((int)scal[9], RCAP);
  int ns1 = min((int)scal[10], RCAP), ne1 = min((int)scal[11], RCAP);
  if (tid < ns0) A[tid] = s0l[tid];
  if (tid < ne0) B[tid] = e0l[tid];
  if (tid < ns1) C[tid] = s1l[tid];
  if (tid < ne1) D[tid] = e1l[tid];
  __syncthreads();
  ranksort(A, ns0, tid, tmp);
  ranksort(B, ne0, tid, tmp);
  ranksort(C, ns1, tid, tmp);
  ranksort(D, ne1, tid, tmp);
  float f0_1 = (T > 1) ? f0[1] : 0.0f;
  float f0s_1 = (T > 1) ? f0s[1] : 0.0f;
  __shared__ int m0s, m1s;
  if (tid == 0) {
    m0s = pair_regions_lds(f0_1, T, A, ns0, B, ne0, LA, RA);
  }
  __syncthreads();
  if (tid < m0s) { r0L[tid] = LA[tid]; r0R[tid] = RA[tid]; }
  __syncthreads();
  if (tid == 0) {
    m1s = pair_regions_lds(f0s_1, T, C, ns1, D, ne1, LA, RA);
  }
  __syncthreads();
  if (tid < m1s) { r1L[tid] = LA[tid]; r1R[tid] = RA[tid]; }
  if (tid == 0) { scal[12] = (unsigned)m0s; scal[13] = (unsigned)m1s; }
}

struct FPRes { int w; int i; float corr; float peak; };

// 256-thread block version: 4 lanes per candidate, 2 accumulators per lane
__device__ FPRes find_peak_block(const float* __restrict__ snd, const float* __restrict__ f0, int T,
                                 int i, bool right_dir, int tid,
                                 float* refbuf, double* sdd, float* swf, int* swi) {
  FPRes res;
  double fi = (double)f0[i];
  if (fi < 60.0) fi = 60.0;
  int w = (int)(SRATE / fi);
  if (w < 1) w = 1;
  if (w > WMAX - 1) w = WMAX - 1;
  int s = i - w / 2; if (s < 0) s = 0;
  int cl, cr;
  if (right_dir) {
    cl = (int)((double)i + 0.3 * (double)w);
    cr = (int)((double)i + 0.75 * (double)w);
  } else {
    double al = (double)i - 1.75 * (double)w;
    double bl = (double)i - 1.3 * (double)w;
    cl = (int)al; if (cl < 0) cl = 0;
    cr = (int)bl; if (cr < 0) cr = 0;
  }
  res.w = w;
  if (cl == cr || T - cl < w) { res.corr = -1.0f; res.i = i; res.peak = 0.0f; return res; }
  int nw = (((cr + w) < T ? (cr + w) : T)) - cl - w + 1;
  if (nw < 1) nw = 1;
  int rlen = T - s; if (rlen > w) rlen = w;
  int lane = tid & 63, wv = tid >> 6;
  // stage ref + ref norm^2
  double part = 0.0;
  for (int k = tid; k < w; k += NTW) {
    float v = (k < rlen) ? snd[s + k] : 0.0f;
    refbuf[k] = v;
    part += (double)v * (double)v;
  }
  for (int off = 32; off; off >>= 1) part += __shfl_xor(part, off, 64);
  if (lane == 0) sdd[wv] = part;
  __syncthreads();
  double refden = sqrt(sdd[0] + sdd[1] + sdd[2] + sdd[3]);
  if (refden < 1e-12) refden = 1e-12;
  // candidates: group g = tid>>2 (64 groups), sub-lane = tid&3
  int g = tid >> 2, sub = tid & 3;
  float bestv = -FLT_MAX; int bestr = INT_MAX;
  for (int base = 0; base < nw; base += 64) {
    int r = base + g;
    if (r < nw) {
      const float* seg = snd + cl + r;
      double d0 = 0.0, d1 = 0.0, n0 = 0.0, n1 = 0.0;
      int k = sub;
      for (; k + 4 < w; k += 8) {
        double a0 = (double)seg[k],     b0 = (double)refbuf[k];
        double a1 = (double)seg[k + 4], b1 = (double)refbuf[k + 4];
        d0 += a0 * b0; n0 += a0 * a0;
        d1 += a1 * b1; n1 += a1 * a1;
      }
      for (; k < w; k += 4) { double a = (double)seg[k]; d0 += a * (double)refbuf[k]; n0 += a * a; }
      double dot = d0 + d1, nr2 = n0 + n1;
      dot += __shfl_xor(dot, 1, 64); nr2 += __shfl_xor(nr2, 1, 64);
      dot += __shfl_xor(dot, 2, 64); nr2 += __shfl_xor(nr2, 2, 64);
      if (sub == 0) {
        double den = sqrt(nr2); if (den < 1e-12) den = 1e-12;
        float c = (float)(dot / (den * refden));
        if (c > bestv) { bestv = c; bestr = r; }
      }
    }
  }
  // wave argmax (non-leader lanes hold -FLT_MAX / INT_MAX), then cross-wave
  for (int off = 32; off; off >>= 1) {
    float ov = __shfl_xor(bestv, off, 64);
    int orr = __shfl_xor(bestr, off, 64);
    if (ov > bestv || (ov == bestv && orr < bestr)) { bestv = ov; bestr = orr; }
  }
  if (lane == 0) { swf[wv] = bestv; swi[wv] = bestr; }
  __syncthreads();
  float bv = swf[0]; int br = swi[0];
  for (int q = 1; q < 4; q++) {
    float ov = swf[q]; int orr = swi[q];
    if (ov > bv || (ov == bv && orr < br)) { bv = ov; br = orr; }
  }
  __syncthreads();  // protect swf/swi reuse below
  // peak = max|seg[br]|
  float pm = 0.0f;
  for (int k = tid; k < w; k += NTW) { float v = fabsf(snd[cl + br + k]); if (v > pm) pm = v; }
  for (int off = 32; off; off >>= 1) { float o = __shfl_xor(pm, off, 64); if (o > pm) pm = o; }
  if (lane == 0) swf[wv] = pm;
  __syncthreads();
  float peak = fmaxf(fmaxf(swf[0], swf[1]), fmaxf(swf[2], swf[3]));
  __syncthreads();  // protect LDS reuse across calls
  res.corr = bv;
  res.i = i + (br + cl) - s;
  res.peak = peak;
  return res;
}

// ---- walks: one block (256 threads) per (region, direction) ----
__global__ __launch_bounds__(NTW) void kwalk(const float* __restrict__ snd, const float* __restrict__ f0,
                                             int T, const unsigned* scal,
                                             const int* __restrict__ r0L, const int* __restrict__ r0R,
                                             int2* __restrict__ lcand, int* __restrict__ lcnt,
                                             int* __restrict__ rpk, int* __restrict__ rcnt) {
  __shared__ float refbuf[WMAX];
  __shared__ double sdd[4];
  __shared__ float swf[8];
  __shared__ int swi[8];
  int tid = threadIdx.x;
  int lane = tid & 63, wv = tid >> 6;
  if (scal[3] == 0u) return;
  int nreg = (int)scal[12];
  float gp = __uint_as_float(scal[0]);
  for (int wid = blockIdx.x; wid < 2 * nreg; wid += gridDim.x) {
    int r = wid >> 1;
    bool rightdir = (wid & 1) != 0;
    int left = r0L[r], right = r0R[r];
    int middle = (left + right) >> 1;
    double fm = (double)f0[middle];
    double wd = SRATE / fm;
    long long wcap = 2LL * (long long)T;
    int w = (wd >= (double)wcap) ? (int)wcap : (int)wd;
    if (w < 1) w = 1;
    int s0 = middle - w / 2; if (s0 < 0) s0 = 0;
    int wlen = w; if (wlen > T - s0) wlen = T - s0;
    float lmn = FLT_MAX; int lmni = INT_MAX;
    float lmx = -FLT_MAX; int lmxi = INT_MAX;
    for (int k = tid; k < wlen; k += NTW) {
      float v = snd[s0 + k];
      if (v < lmn) { lmn = v; lmni = k; }
      if (v > lmx) { lmx = v; lmxi = k; }
    }
    for (int off = 32; off; off >>= 1) {
      float ov = __shfl_xor(lmn, off, 64); int oi = __shfl_xor(lmni, off, 64);
      if (ov < lmn || (ov == lmn && oi < lmni)) { lmn = ov; lmni = oi; }
      float ov2 = __shfl_xor(lmx, off, 64); int oi2 = __shfl_xor(lmxi, off, 64);
      if (ov2 > lmx || (ov2 == lmx && oi2 < lmxi)) { lmx = ov2; lmxi = oi2; }
    }
    if (lane == 0) { swf[wv] = lmn; swi[wv] = lmni; swf[4 + wv] = lmx; swi[4 + wv] = lmxi; }
    __syncthreads();
    float mn = swf[0]; int imn = swi[0];
    float mx = swf[4]; int imx = swi[4];
    for (int q = 1; q < 4; q++) {
      float ov = swf[q]; int oi = swi[q];
      if (ov < mn || (ov == mn && oi < imn)) { mn = ov; imn = oi; }
      float ov2 = swf[4 + q]; int oi2 = swi[4 + q];
      if (ov2 > mx || (ov2 == mx && oi2 < imx)) { mx = ov2; imx = oi2; }
    }
    __syncthreads();
    int i;
    if (mn == mx) i = middle;
    else i = s0 + ((fabsf(mn) > fabsf(mx)) ? imn : imx);
    if (!rightdir) {
      int nl = 0, guard = 0;
      for (;;) {
        if (++guard > 500000) break;
        FPRes p = find_peak_block(snd, f0, T, i, false, tid, refbuf, sdd, swf, swi);
        i = p.i;
        if (p.corr == -1.0f) i -= p.w;
        if (i < left) {
          if ((double)p.corr > 0.7 && (double)p.peak > 0.023333 * (double)gp) {
            if (nl < LCR) { if (tid == 0) lcand[r * LCR + nl] = make_int2(i, p.w); nl++; }
          }
          break;
        }
        if ((double)p.corr > 0.3 && (p.peak == 0.0f || (double)p.peak > 0.01 * (double)gp)) {
          if (nl < LCR) { if (tid == 0) lcand[r * LCR + nl] = make_int2(i, p.w); nl++; }
        }
      }
      if (tid == 0) lcnt[r] = nl;
    } else {
      int nr = 0, guard = 0;
      for (;;) {
        if (++guard > 500000) break;
        FPRes p = find_peak_block(snd, f0, T, i, true, tid, refbuf, sdd, swf, swi);
        i = p.i;
        if (p.corr == -1.0f) i += p.w;
        if (i >= right) {
          if ((double)p.corr > 0.7 && (double)p.peak > 0.023333 * (double)gp) {
            if (nr < RCR) { if (tid == 0) rpk[r * RCR + nr] = i; nr++; }
          }
          break;
        }
        if ((double)p.corr > 0.3 && (p.peak == 0.0f || (double)p.peak > 0.01 * (double)gp)) {
          if (nr < RCR) { if (tid == 0) rpk[r * RCR + nr] = i; nr++; }
        }
      }
      if (tid == 0) rcnt[r] = nr;
    }
  }
}

// ---- merge: added_right prefix + filter + assemble + LDS bitonic sort + clip ----
__global__ __launch_bounds__(256) void kmerge(int T, unsigned* scal,
                                              const int2* __restrict__ lcand, const int* __restrict__ lcnt,
                                              const int* __restrict__ rpk, const int* __restrict__ rcnt,
                                              int* __restrict__ peaks) {
  __shared__ long long arR[RCAP];
  __shared__ long long lastR[RCAP];
  __shared__ int rcs[RCAP];
  __shared__ int lcs[RCAP];
  __shared__ int klc[RCAP];
  __shared__ int off[RCAP + 1];
  __shared__ int sbuf[SCAP];
  int tid = threadIdx.x;
  int nreg = (int)scal[12];
  if (scal[3] == 0u || nreg == 0) { if (tid == 0) scal[4] = 0u; return; }
  if (tid < nreg) {
    int rc = rcnt[tid];
    rcs[tid] = rc;
    lcs[tid] = lcnt[tid];
    lastR[tid] = (rc > 0) ? (long long)rpk[tid * RCR + rc - 1] : LLONG_MIN;
  }
  __syncthreads();
  if (tid == 0) {
    long long ar = -(1LL << 62);
    for (int r = 0; r < nreg; r++) { arR[r] = ar; if (rcs[r] > 0) ar = lastR[r]; }
  }
  __syncthreads();
  if (tid < nreg) {
    int r = tid, n = lcs[r], c = 0;
    long long ar = arR[r];
    for (int j = 0; j < n; j++) {
      int2 cd = lcand[r * LCR + j];
      if ((double)((long long)cd.x - ar) > 0.8 * (double)cd.y) c++;
    }
    klc[r] = c;
  }
  __syncthreads();
  if (tid == 0) {
    int acc = 0;
    for (int r = 0; r < nreg; r++) { off[r] = acc; acc += klc[r] + rcs[r]; if (acc > SCAP) acc = SCAP; }
    off[nreg] = acc;
    scal[4] = (unsigned)acc;
  }
  __syncthreads();
  if (tid < nreg) {
    int r = tid;
    long long ar = arR[r];
    int n = lcs[r], pos = off[r];
    for (int j = n - 1; j >= 0; j--) {
      int2 cd = lcand[r * LCR + j];
      if ((double)((long long)cd.x - ar) > 0.8 * (double)cd.y) { if (pos < SCAP) peaks[pos] = cd.x; pos++; }
    }
    int rc = rcs[r];
    for (int j = 0; j < rc; j++) { if (pos < SCAP) peaks[pos] = rpk[r * RCR + j]; pos++; }
  }
  __syncthreads();
  int npk = off[nreg];
  if (npk > 1) {
    int n2 = 1; while (n2 < npk) n2 <<= 1;
    for (int k = tid; k < n2; k += 256) sbuf[k] = (k < npk) ? peaks[k] : INT_MAX;
    __syncthreads();
    for (int kk = 2; kk <= n2; kk <<= 1) {
      for (int j = kk >> 1; j > 0; j >>= 1) {
        for (int idx = tid; idx < n2; idx += 256) {
          int ixj = idx ^ j;
          if (ixj > idx) {
            int a = sbuf[idx], b = sbuf[ixj];
            bool up = ((idx & kk) == 0);
            if ((up && a > b) || (!up && a < b)) { sbuf[idx] = b; sbuf[ixj] = a; }
          }
        }
        __syncthreads();
      }
    }
    for (int k = tid; k < npk; k += 256) peaks[k] = sbuf[k];
    __syncthreads();
  }
  for (int k = tid; k < npk; k += 256) { int v = peaks[k]; if (v < 0) v = 0; if (v > T - 1) v = T - 1; peaks[k] = v; }
}

// ---- psola plan: one thread per region ----
// Monotone-pointer rewrite: lv strictly increases within a region, so
// lower_bound(P, lv) is non-decreasing. One binary search per region to
// init `lo`, then incremental advance (~1-3 LDS reads/iter instead of
// 2 full binary searches = ~26 dependent LDS reads/iter).
// `p` derived directly: target is exactly P[lo-1] (if d0<=d1) or P[lo];
// the original second lower_bound reduces to "first occurrence of that
// value", reproduced by a backward duplicate scan.
__global__ __launch_bounds__(128) void kplan(const float* __restrict__ f0s, int T, unsigned* scal,
                                             const int* __restrict__ peaks,
                                             const int* __restrict__ r1L, const int* __restrict__ r1R,
                                             int4* __restrict__ ops, int* __restrict__ opcnt) {
  __shared__ int sp[SLDS];
  int tid = threadIdx.x;
  int npk = (int)scal[4];
  int nreg = (int)scal[13];
  if (scal[3] == 0u || npk == 0) {
    if (tid == 0) { scal[6] = 0u; scal[14] = 0u; }
    return;
  }
  const int* P = peaks;
  if (npk <= SLDS) {
    for (int k = tid; k < npk; k += 128) sp[k] = peaks[k];
    __syncthreads();
    P = sp;
  }
  double minpos = (double)__uint_as_float(scal[1]);
  double max_w = 1.25 * SRATE / minpos;
  for (int r = tid; r < nreg; r += 128) {
    int prev_right = (r == 0) ? 0 : r1R[r - 1];
    int left_v = r1L[r], right_v = r1R[r];
    int c = 0;
    if (prev_right < left_v) {
      ops[r * OPR + c] = make_int4(prev_right, prev_right, left_v - prev_right, left_v - prev_right);
      c++;
    }
    int lv = left_v, guard = 0;
    int lo = -1;  // monotone lower_bound pointer; invariant: P[m] < x for all m < lo, and (lo==npk || P[lo] >= x)
    while (lv < right_v) {
      if (++guard > 500000) break;
      float fraw = f0s[lv];  // issue global load early; latency hides under pointer work
      int x = lv;
      if (lo < 0) {
        int a = 0, b = npk;
        while (a < b) { int m = (a + b) >> 1; if (P[m] < x) a = m + 1; else b = m; }
        lo = a;
      } else {
        while (lo < npk && P[lo] < x) lo++;
      }
      long long d0 = (lo > 0) ? (long long)x - (long long)P[lo - 1] : LLONG_MAX;
      long long d1 = (lo < npk) ? (long long)P[lo] - (long long)x : LLONG_MAX;
      int p;
      if (d0 <= d1) {
        // target = P[lo-1]; original lower_bound(target) = first occurrence of that value
        p = lo - 1;
        int tv = P[p];
        while (p > 0 && P[p - 1] == tv) p--;
      } else {
        // target = P[lo]; P[lo-1] < x <= P[lo] so lo is already the first occurrence
        p = lo;
      }
      double f = (double)fraw; if (f < 60.0) f = 60.0;
      int period = (int)(SRATE / f);
      int lw = period >> 1, rw = period >> 1;
      if (p > 0) { long long g = (long long)P[p] - (long long)P[p - 1]; if ((double)g <= max_w && g < (long long)lw) lw = (int)g; }
      if (p < npk - 1) { long long g = (long long)P[p + 1] - (long long)P[p]; if ((double)g <= max_w && g < (long long)rw) rw = (int)g; }
      int left_i = P[p] - lw; if (left_i < 0) left_i = 0;
      int right_i = P[p] + rw;
      int ival = (right_i - left_i) >> 1;
      if (ival <= 0) break;
      int a0 = lv - ival;
      int len1 = 0;
      if (a0 >= 0) { int e = lv + ival; if (e > T) e = T; len1 = e - a0; if (len1 < 0) len1 = 0; }
      int e2 = left_i + 2 * ival; if (e2 > T) e2 = T;
      int len2 = e2 - left_i; if (len2 < 0) len2 = 0;
      int seglen = len1 < len2 ? len1 : len2;
      int len_dst = (a0 < 0) ? 0 : ((T - a0 < seglen) ? T - a0 : seglen);
      int len_src = (T - left_i < seglen) ? T - left_i : seglen;
      int L = seglen; if (len_dst < L) L = len_dst; if (len_src < L) L = len_src;
      if (L > 0 && c < OPR) { ops[r * OPR + c] = make_int4(a0, left_i, L, 2 * ival); c++; }
      lv += 2 * ival;
    }
    opcnt[r] = c;
  }
  if (tid == 0) {
    scal[6] = (nreg > 0) ? (unsigned)r1R[nreg - 1] : 0u;
    scal[14] = (unsigned)nreg;
  }
}

// ---- overlap-add scatter ----
__global__ __launch_bounds__(256) void kapply(const float* __restrict__ snd, float* __restrict__ out,
                                              const unsigned* scal, const int4* __restrict__ ops,
                                              const int* __restrict__ opcnt) {
  int nreg = (int)scal[14];
  int total = nreg * OPR;
  for (int slot = blockIdx.x; slot < total; slot += gridDim.x) {
    int r = slot / OPR, j = slot - r * OPR;
    if (j >= opcnt[r]) continue;
    int4 o = ops[r * OPR + j];
    double nn = (double)o.w;
    for (int k = threadIdx.x; k < o.z; k += blockDim.x) {
      double cph = (6.283185307179586 * (double)k) / nn;
      float wv = (float)(0.5 - 0.5 * cos(cph));
      atomicAdd(out + o.x + k, __fmul_rn(wv, snd[o.y + k]));
    }
  }
}

// ---- tail copy ----
__global__ __launch_bounds__(256) void ktail(const float* __restrict__ snd, float* __restrict__ out,
                                             const unsigned* scal, int T) {
  int tail = (int)scal[6];
  int stride = gridDim.x * blockDim.x;
  for (int t = blockIdx.x * blockDim.x + threadIdx.x; t < T; t += stride)
    if (t >= tail) out[t] = snd[t];
}

extern "C" void kernel_launch(void* const* d_in, const int* in_sizes, int n_in,
                              void* d_out, int out_size, void* d_ws, size_t ws_size,
                              hipStream_t stream) {
  (void)n_in; (void)ws_size;
  int T = in_sizes[0];
  int S = in_sizes[1];
  const float* snd = (const float*)d_in[0];
  const float* pitch = (const float*)d_in[1];
  const int* steps = (const int*)d_in[2];
  const float* prange = (const float*)d_in[3];
  float* out = (float*)d_out;

  char* base = (char*)d_ws;
  size_t off = 0;
  auto alloc = [&](size_t bytes, size_t align) -> char* {
    off = (off + align - 1) & ~(align - 1);
    char* p = base + off;
    off += bytes;
    return p;
  };
  float* f0  = (float*)alloc((size_t)T * 4, 16);
  float* f0s = (float*)alloc((size_t)T * 4, 16);
  unsigned* scal = (unsigned*)alloc(256, 16);
  int* s0l = (int*)alloc(RCAP * 4, 4);
  int* e0l = (int*)alloc(RCAP * 4, 4);
  int* s1l = (int*)alloc(RCAP * 4, 4);
  int* e1l = (int*)alloc(RCAP * 4, 4);
  int* r0L = (int*)alloc(RCAP * 4, 4);
  int* r0R = (int*)alloc(RCAP * 4, 4);
  int* r1L = (int*)alloc(RCAP * 4, 4);
  int* r1R = (int*)alloc(RCAP * 4, 4);
  int* lcnt = (int*)alloc(RCAP * 4, 4);
  int* rcnt = (int*)alloc(RCAP * 4, 4);
  int* opcnt = (int*)alloc(RCAP * 4, 4);
  int2* lcand = (int2*)alloc((size_t)RCAP * LCR * 8, 8);
  int* rpk = (int*)alloc((size_t)RCAP * RCR * 4, 4);
  int* peaks = (int*)alloc((size_t)SCAP * 4, 4);
  int4* ops = (int4*)alloc((size_t)RCAP * OPR * 16, 16);

  hipMemsetAsync(d_out, 0, (size_t)out_size * sizeof(float), stream);
  kinit_stats<<<1, 256, 0, stream>>>(pitch, S, scal);
  kmedsel<<<(S + 511) / 512, 512, 0, stream>>>(pitch, S, scal);
  kprep<<<1024, 256, 0, stream>>>(pitch, S, T, snd, scal, steps, prange, f0, f0s, s0l, e0l, s1l, e1l);
  kregsort2<<<1, 128, 0, stream>>>(f0, f0s, T, scal, s0l, e0l, s1l, e1l, r0L, r0R, r1L, r1R);
  kwalk<<<256, NTW, 0, stream>>>(snd, f0, T, scal, r0L, r0R, lcand, lcnt, rpk, rcnt);
  kmerge<<<1, 256, 0, stream>>>(T, scal, lcand, lcnt, rpk, rcnt, peaks);
  kplan<<<1, 128, 0, stream>>>(f0s, T, scal, peaks, r1L, r1R, ops, opcnt);
  kapply<<<2048, 256, 0, stream>>>(snd, out, scal, ops, opcnt);
  ktail<<<1024, 256, 0, stream>>>(snd, out, scal, T);
}